// Round 2
// baseline (1007.352 us; speedup 1.0000x reference)
//
#include <hip/hip_runtime.h>

#define N_ROWS 65536
#define NE 1024
#define ED 64
#define NCH 4
#define CHJ 256   // NE / NCH

static const size_t OFF_ZQ = 1;
static const size_t OFF_ME = 1 + 4194304;
static const size_t OFF_IDX = OFF_ME + (size_t)N_ROWS * NE;

// ---- e2[j] = numpy pairwise sum of cb[j]*cb[j] (bit-exact emulation) ----
__global__ void k_e2(const float* __restrict__ cb, float* __restrict__ e2,
                     double* __restrict__ lsum) {
  const int j = blockIdx.x * 64 + threadIdx.x;
  if (blockIdx.x == 0 && threadIdx.x == 0) *lsum = 0.0;
  if (j >= NE) return;
  const float* __restrict__ e = cb + (size_t)j * ED;
  float r[8];
  #pragma unroll
  for (int i = 0; i < 8; ++i) {
    float v = e[i];
    float q = v * v;
    asm volatile("" : "+v"(q));        // block FMA contraction (numpy rounds the mul)
    r[i] = q;
  }
  #pragma unroll
  for (int k = 1; k < 8; ++k) {
    #pragma unroll
    for (int i = 0; i < 8; ++i) {
      float v = e[8 * k + i];
      float q = v * v;
      asm volatile("" : "+v"(q));
      r[i] += q;
    }
  }
  e2[j] = ((r[0] + r[1]) + (r[2] + r[3])) + ((r[4] + r[5]) + (r[6] + r[7]));
}

// ---- distances + first-index argmin, bit-exact numpy/BLAS emulation ----
__global__ __launch_bounds__(256) void k_dist(const float* __restrict__ z,
    const float* __restrict__ cb, const float* __restrict__ e2,
    float* __restrict__ idxf) {
  __shared__ float s_d[NCH][64];
  __shared__ int   s_i[NCH][64];
  const int lane = threadIdx.x & 63;
  const int wv   = threadIdx.x >> 6;           // chunk id 0..3
  const int n    = blockIdx.x * 64 + lane;
  const int b = n >> 10, hw = n & 1023;
  const float* __restrict__ zp = z + (size_t)b * 65536 + hw;
  float zr[ED];
  #pragma unroll
  for (int d = 0; d < ED; ++d) zr[d] = zp[(size_t)d << 10];

  // z2 = numpy pairwise sum of zr*zr
  float r[8];
  #pragma unroll
  for (int i = 0; i < 8; ++i) {
    float q = zr[i] * zr[i];
    asm volatile("" : "+v"(q));
    r[i] = q;
  }
  #pragma unroll
  for (int k = 1; k < 8; ++k) {
    #pragma unroll
    for (int i = 0; i < 8; ++i) {
      float q = zr[8 * k + i] * zr[8 * k + i];
      asm volatile("" : "+v"(q));
      r[i] += q;
    }
  }
  const float z2 = ((r[0] + r[1]) + (r[2] + r[3])) + ((r[4] + r[5]) + (r[6] + r[7]));

  float best = 1e30f;
  int bidx = 0;
  const int j0 = wv * CHJ;
  for (int jj = 0; jj < CHJ; ++jj) {
    const int j = j0 + jj;
    const int ju = __builtin_amdgcn_readfirstlane(j);   // scalarize codebook addr
    const float* __restrict__ e = cb + (size_t)ju * ED;
    float acc = 0.0f;
    #pragma unroll
    for (int k = 0; k < ED; ++k) acc = fmaf(zr[k], e[k], acc);  // BLAS: sequential f32 FMA chain
    const float t = z2 + e2[ju];          // fl(z2 + e2)
    const float d = t - 2.0f * acc;       // fl(t - 2*dot)  (x2 exact; fma-fusion equivalent)
    if (d < best) { best = d; bidx = j; } // strict < == numpy first-index argmin
  }
  s_d[wv][lane] = best;
  s_i[wv][lane] = bidx;
  __syncthreads();
  if (wv == 0) {
    float bb = s_d[0][lane];
    int   bi = s_i[0][lane];
    #pragma unroll
    for (int c = 1; c < NCH; ++c) {
      const float dd = s_d[c][lane];
      if (dd < bb) { bb = dd; bi = s_i[c][lane]; }  // ascending chunks => lowest index on tie
    }
    idxf[n] = (float)bi;
  }
}

__global__ void k_onehot(const float* __restrict__ idxf, float* __restrict__ me) {
  const int n = blockIdx.x;
  const int idx = (int)idxf[n];
  float* __restrict__ row = me + (size_t)n * NE;
  #pragma unroll
  for (int p = 0; p < 4; ++p) {
    const int i = (p << 8) + threadIdx.x;
    row[i] = (i == idx) ? 1.0f : 0.0f;
  }
}

__global__ void k_zq(const float* __restrict__ z, const float* __restrict__ cb,
                     const float* __restrict__ idxf, float* __restrict__ zq,
                     double* __restrict__ lsum) {
  const int o = blockIdx.x * 256 + threadIdx.x;   // < 4194304
  const int b = o >> 16;
  const int d = (o >> 10) & 63;
  const int hw = o & 1023;
  const int n = (b << 10) + hw;
  const int idx = (int)idxf[n];
  const float v = cb[(size_t)idx * ED + d];
  zq[o] = v;
  const float diff = z[o] - v;
  float s = diff * diff;
  #pragma unroll
  for (int off = 32; off > 0; off >>= 1) s += __shfl_xor(s, off, 64);
  if ((threadIdx.x & 63) == 0) atomicAdd(lsum, (double)s);
}

__global__ void k_final(const double* __restrict__ lsum, float* __restrict__ out0) {
  if (threadIdx.x == 0)
    out0[0] = (float)(1.25 * (*lsum) / 4194304.0);
}

extern "C" void kernel_launch(void* const* d_in, const int* in_sizes, int n_in,
                              void* d_out, int out_size, void* d_ws, size_t ws_size,
                              hipStream_t stream) {
  const float* z  = (const float*)d_in[0];
  const float* cb = (const float*)d_in[1];
  float* out  = (float*)d_out;
  float* zq   = out + OFF_ZQ;
  float* me   = out + OFF_ME;
  float* idxf = out + OFF_IDX;
  double* lsum = (double*)d_ws;
  float* e2 = (float*)((char*)d_ws + 16);

  k_e2<<<16, 64, 0, stream>>>(cb, e2, lsum);
  k_dist<<<N_ROWS / 64, 256, 0, stream>>>(z, cb, e2, idxf);
  k_onehot<<<N_ROWS, 256, 0, stream>>>(idxf, me);
  k_zq<<<16384, 256, 0, stream>>>(z, cb, idxf, zq, lsum);
  k_final<<<1, 64, 0, stream>>>(lsum, out);
}

// Round 3
// 241.158 us; speedup vs baseline: 4.1771x; 4.1771x over previous
//
#include <hip/hip_runtime.h>

#define N_ROWS 65536
#define NE 1024
#define ED 64
#define NCH 4
#define CHJ 256   // NE / NCH

static const size_t OFF_ZQ = 1;
static const size_t OFF_ME = 1 + 4194304;
static const size_t OFF_IDX = OFF_ME + (size_t)N_ROWS * NE;
#define ME_FLOATS ((size_t)N_ROWS * NE)   // 67108864
#define NBLK_ZQ 16384

// ---- e2[j] = numpy pairwise sum of cb[j]*cb[j] (bit-exact emulation) ----
__global__ void k_e2(const float* __restrict__ cb, float* __restrict__ e2) {
  const int j = blockIdx.x * 64 + threadIdx.x;
  if (j >= NE) return;
  const float* __restrict__ e = cb + (size_t)j * ED;
  float r[8];
  #pragma unroll
  for (int i = 0; i < 8; ++i) {
    float v = e[i];
    float q = v * v;
    asm volatile("" : "+v"(q));        // block FMA contraction (numpy rounds the mul)
    r[i] = q;
  }
  #pragma unroll
  for (int k = 1; k < 8; ++k) {
    #pragma unroll
    for (int i = 0; i < 8; ++i) {
      float v = e[8 * k + i];
      float q = v * v;
      asm volatile("" : "+v"(q));
      r[i] += q;
    }
  }
  e2[j] = ((r[0] + r[1]) + (r[2] + r[3])) + ((r[4] + r[5]) + (r[6] + r[7]));
}

// ---- distances + first-index argmin, bit-exact numpy/BLAS emulation ----
__global__ __launch_bounds__(256) void k_dist(const float* __restrict__ z,
    const float* __restrict__ cb, const float* __restrict__ e2,
    float* __restrict__ idxf) {
  __shared__ float s_d[NCH][64];
  __shared__ int   s_i[NCH][64];
  const int lane = threadIdx.x & 63;
  const int wv   = threadIdx.x >> 6;           // chunk id 0..3
  const int n    = blockIdx.x * 64 + lane;
  const int b = n >> 10, hw = n & 1023;
  const float* __restrict__ zp = z + (size_t)b * 65536 + hw;
  float zr[ED];
  #pragma unroll
  for (int d = 0; d < ED; ++d) zr[d] = zp[(size_t)d << 10];

  // z2 = numpy pairwise sum of zr*zr
  float r[8];
  #pragma unroll
  for (int i = 0; i < 8; ++i) {
    float q = zr[i] * zr[i];
    asm volatile("" : "+v"(q));
    r[i] = q;
  }
  #pragma unroll
  for (int k = 1; k < 8; ++k) {
    #pragma unroll
    for (int i = 0; i < 8; ++i) {
      float q = zr[8 * k + i] * zr[8 * k + i];
      asm volatile("" : "+v"(q));
      r[i] += q;
    }
  }
  const float z2 = ((r[0] + r[1]) + (r[2] + r[3])) + ((r[4] + r[5]) + (r[6] + r[7]));

  float best = 1e30f;
  int bidx = 0;
  const int j0 = wv * CHJ;
  for (int jj = 0; jj < CHJ; ++jj) {
    const int j = j0 + jj;
    const int ju = __builtin_amdgcn_readfirstlane(j);   // scalarize codebook addr
    const float* __restrict__ e = cb + (size_t)ju * ED;
    float acc = 0.0f;
    #pragma unroll
    for (int k = 0; k < ED; ++k) acc = fmaf(zr[k], e[k], acc);  // BLAS: sequential f32 FMA chain
    const float t = z2 + e2[ju];          // fl(z2 + e2)
    const float d = t - 2.0f * acc;       // fl(t - 2*dot)
    if (d < best) { best = d; bidx = j; } // strict < == numpy first-index argmin
  }
  s_d[wv][lane] = best;
  s_i[wv][lane] = bidx;
  __syncthreads();
  if (wv == 0) {
    float bb = s_d[0][lane];
    int   bi = s_i[0][lane];
    #pragma unroll
    for (int c = 1; c < NCH; ++c) {
      const float dd = s_d[c][lane];
      if (dd < bb) { bb = dd; bi = s_i[c][lane]; }  // ascending chunks => lowest index on tie
    }
    idxf[n] = (float)bi;
  }
}

// ---- z_q gather + per-block loss partial (NO global atomics) ----
__global__ __launch_bounds__(256) void k_zq(const float* __restrict__ z,
    const float* __restrict__ cb, const float* __restrict__ idxf,
    float* __restrict__ zq, float* __restrict__ partial) {
  const int o = blockIdx.x * 256 + threadIdx.x;   // < 4194304
  const int b = o >> 16;
  const int d = (o >> 10) & 63;
  const int hw = o & 1023;
  const int n = (b << 10) + hw;
  const int idx = (int)idxf[n];
  const float v = cb[(size_t)idx * ED + d];
  zq[o] = v;
  const float diff = z[o] - v;
  float s = diff * diff;
  #pragma unroll
  for (int off = 32; off > 0; off >>= 1) s += __shfl_xor(s, off, 64);
  __shared__ float sh[4];
  if ((threadIdx.x & 63) == 0) sh[threadIdx.x >> 6] = s;
  __syncthreads();
  if (threadIdx.x == 0)
    partial[blockIdx.x] = (sh[0] + sh[1]) + (sh[2] + sh[3]);
}

__global__ void k_loss(const float* __restrict__ partial, float* __restrict__ out0) {
  const int t = threadIdx.x;  // 256 threads
  double s = 0.0;
  #pragma unroll
  for (int k = 0; k < NBLK_ZQ / 256; ++k) s += (double)partial[t + (k << 8)];
  #pragma unroll
  for (int off = 32; off > 0; off >>= 1) s += __shfl_xor(s, off, 64);
  __shared__ double sh[4];
  if ((t & 63) == 0) sh[t >> 6] = s;
  __syncthreads();
  if (t == 0)
    out0[0] = (float)(1.25 * ((sh[0] + sh[1]) + (sh[2] + sh[3])) / 4194304.0);
}

// ---- zero-fill the one-hot region with float4 stores ----
__global__ __launch_bounds__(256) void k_fill(float* __restrict__ me) {
  // me byte address is ODD*4 => me+3 is 16B-aligned.
  const size_t n4 = (ME_FLOATS - 3) >> 2;          // # of float4 slots from me+3
  float4* __restrict__ p4 = reinterpret_cast<float4*>(me + 3);
  const size_t stride = (size_t)gridDim.x * blockDim.x;
  const float4 zero4 = make_float4(0.f, 0.f, 0.f, 0.f);
  for (size_t i = blockIdx.x * (size_t)blockDim.x + threadIdx.x; i < n4; i += stride)
    p4[i] = zero4;
  if (blockIdx.x == 0 && threadIdx.x == 0) {
    me[0] = 0.f; me[1] = 0.f; me[2] = 0.f;
    me[ME_FLOATS - 1] = 0.f;
  }
}

__global__ void k_scatter(const float* __restrict__ idxf, float* __restrict__ me) {
  const int n = blockIdx.x * 256 + threadIdx.x;
  const int idx = (int)idxf[n];
  me[(size_t)n * NE + idx] = 1.0f;
}

extern "C" void kernel_launch(void* const* d_in, const int* in_sizes, int n_in,
                              void* d_out, int out_size, void* d_ws, size_t ws_size,
                              hipStream_t stream) {
  const float* z  = (const float*)d_in[0];
  const float* cb = (const float*)d_in[1];
  float* out  = (float*)d_out;
  float* zq   = out + OFF_ZQ;
  float* me   = out + OFF_ME;
  float* idxf = out + OFF_IDX;
  float* e2 = (float*)((char*)d_ws + 16);
  float* partial = me;   // staged in the one-hot region, consumed by k_loss before k_fill

  k_e2<<<16, 64, 0, stream>>>(cb, e2);
  k_dist<<<N_ROWS / 64, 256, 0, stream>>>(z, cb, e2, idxf);
  k_zq<<<NBLK_ZQ, 256, 0, stream>>>(z, cb, idxf, zq, partial);
  k_loss<<<1, 256, 0, stream>>>(partial, out);
  k_fill<<<2048, 256, 0, stream>>>(me);
  k_scatter<<<N_ROWS / 256, 256, 0, stream>>>(idxf, me);
}